// Round 9
// baseline (184.768 us; speedup 1.0000x reference)
//
#include <hip/hip_runtime.h>
#include <math.h>

// Problem constants (fixed by setup_inputs)
constexpr int Bb = 4, Hc = 64, Wc = 64, Cc = 256, Cf = 128, E = 64, KK = 25, F = 256;
constexpr int Hf = 128, Wf = 128;
constexpr int Nc = Bb * Hc * Wc;   // 16384 coarse pixels
constexpr int Nf = Bb * Hf * Wf;   // 65536 fine pixels

typedef __attribute__((ext_vector_type(8))) short bf16x8;
typedef __attribute__((ext_vector_type(4))) float f32x4;

__device__ inline unsigned short f2b(float f) {
  union { float f; unsigned u; } v; v.f = f;
  return (unsigned short)((v.u + 0x7FFF + ((v.u >> 16) & 1)) >> 16);
}

// ---------------------------------------------------------------------------
// prep1: blocks 0..31 wprep (W1,W2 -> Wt1,Wt2); 32..34 sprep; 35.. gate
__global__ __launch_bounds__(256) void prep1_kernel(
    const float* __restrict__ W1, const float* __restrict__ W2,
    unsigned short* __restrict__ Wt1, unsigned short* __restrict__ Wt2,
    const float* __restrict__ fw, const float* __restrict__ cw,
    const float* __restrict__ cntw, unsigned short* __restrict__ Wtf,
    unsigned short* __restrict__ Wtc, unsigned short* __restrict__ Wtcnt,
    const float* __restrict__ coarse, const float* __restrict__ gw,
    const float* __restrict__ gb, float* __restrict__ gatec) {
  __shared__ float tile[64][65];
  int idx = blockIdx.x, t = threadIdx.x;
  if (idx < 32) {
    const float* W = (idx >= 16) ? W2 : W1;
    unsigned short* Wt = (idx >= 16) ? Wt2 : Wt1;
    int k0 = ((idx >> 2) & 3) * 64, n0 = (idx & 3) * 64;
    int r0 = t >> 6, c = t & 63;
    for (int r = r0; r < 64; r += 4)
      tile[r][c] = W[(size_t)(k0 + r) * 256 + n0 + c];
    __syncthreads();
    for (int r = r0; r < 64; r += 4)
      Wt[(size_t)(n0 + r) * 256 + k0 + c] = f2b(tile[c][r]);
  } else if (idx < 35) {
    int sec = idx - 32;
    if (sec == 0) {
      for (int i = t; i < 64 * 128; i += 256) {
        int n = i & 63, k = i >> 6;
        Wtf[n * 128 + k] = f2b(fw[k * 64 + n]);
      }
    } else if (sec == 1) {
      for (int i = t; i < 64 * 256; i += 256) {
        int n = i & 63, k = i >> 6;
        Wtc[n * 256 + k] = f2b(cw[k * 64 + n]);
      }
    } else {
      for (int i = t; i < 32 * 576; i += 256) {
        int n = i & 31, kk = i >> 5;
        Wtcnt[n * 576 + kk] = (n < 25) ? f2b(cntw[kk * 25 + n]) : (unsigned short)0;
      }
    }
  } else {
    int px = (idx - 35) * 4 + (t >> 6);
    int lane = t & 63;
    const float4 a = *(const float4*)(coarse + (size_t)px * 256 + lane * 4);
    const float4 w = *(const float4*)(gw + lane * 4);
    float v = a.x * w.x + a.y * w.y + a.z * w.z + a.w * w.w;
    #pragma unroll
    for (int off = 32; off; off >>= 1) v += __shfl_xor(v, off);
    if (lane == 0) gatec[px] = 1.f / (1.f + expf(-(v + gb[0])));
  }
}

// ---------------------------------------------------------------------------
// prep2: blocks 0..15 Wt12[n][k]=(W1@W2)^T bf16 via MFMA; block 16: b12
__global__ __launch_bounds__(256) void prep2_kernel(
    const float* __restrict__ W1, const unsigned short* __restrict__ Wt2,
    unsigned short* __restrict__ Wt12, const float* __restrict__ b1,
    const float* __restrict__ W2, const float* __restrict__ b2,
    float* __restrict__ b12f) {
  __shared__ __align__(16) unsigned short a_s[64 * 264];
  int idx = blockIdx.x, t = threadIdx.x;
  if (idx == 16) {
    int n = t;
    float acc = b2[n];
    #pragma unroll 8
    for (int m = 0; m < 256; m++) acc += b1[m] * W2[(size_t)m * 256 + n];
    b12f[n] = acc;
    return;
  }
  int nbase = (idx & 3) * 64, k0 = (idx >> 2) * 64;
  for (int i = t; i < 64 * 64; i += 256) {
    int row = i >> 6, mc = i & 63;
    float4 v = *(const float4*)&W1[(size_t)(k0 + row) * 256 + mc * 4];
    *(short4*)&a_s[row * 264 + mc * 4] =
        make_short4((short)f2b(v.x), (short)f2b(v.y), (short)f2b(v.z), (short)f2b(v.w));
  }
  __syncthreads();
  int wid = t >> 6, lane = t & 63;
  int lr = lane & 15, lg = lane >> 4;
  const f32x4 zero4 = {0.f, 0.f, 0.f, 0.f};
  f32x4 acc[4] = {zero4, zero4, zero4, zero4};
  #pragma unroll
  for (int kt = 0; kt < 8; kt++) {
    bf16x8 a = *(const bf16x8*)&a_s[(wid * 16 + lr) * 264 + kt * 32 + lg * 8];
    #pragma unroll
    for (int nt = 0; nt < 4; nt++) {
      bf16x8 bb = *(const bf16x8*)&Wt2[(size_t)(nbase + nt * 16 + lr) * 256 + kt * 32 + lg * 8];
      acc[nt] = __builtin_amdgcn_mfma_f32_16x16x32_bf16(a, bb, acc[nt], 0, 0, 0);
    }
  }
  #pragma unroll
  for (int nt = 0; nt < 4; nt++)
    #pragma unroll
    for (int r = 0; r < 4; r++)
      Wt12[(size_t)(nbase + nt * 16 + lr) * 256 + k0 + wid * 16 + lg * 4 + r] =
          f2b(acc[nt][r]);
}

// ---------------------------------------------------------------------------
// emb (both resolutions): out_bf16[px][64] = in[px][K] @ Wt[64][K]
template <int K>
__device__ inline void emb_body(const float* __restrict__ in,
                                const unsigned short* __restrict__ Wt,
                                const float* __restrict__ bias,
                                unsigned short* __restrict__ out, int pxb,
                                unsigned short* a_s) {
  constexpr int LDA = K + 8;
  int t = threadIdx.x;
  constexpr int KC = K / 4;
  for (int idx = t; idx < 64 * KC; idx += 256) {
    int px = idx / KC, kc = idx % KC;
    float4 v = *(const float4*)&in[(size_t)(pxb + px) * K + kc * 4];
    *(short4*)&a_s[px * LDA + kc * 4] =
        make_short4((short)f2b(v.x), (short)f2b(v.y), (short)f2b(v.z), (short)f2b(v.w));
  }
  __syncthreads();

  int wid = t >> 6, lane = t & 63;
  int lr = lane & 15, lg = lane >> 4;
  const f32x4 zero4 = {0.f, 0.f, 0.f, 0.f};
  f32x4 acc[4] = {zero4, zero4, zero4, zero4};

  #pragma unroll
  for (int kt = 0; kt < K / 32; kt++) {
    bf16x8 a = *(const bf16x8*)&a_s[(wid * 16 + lr) * LDA + kt * 32 + lg * 8];
    #pragma unroll
    for (int nt = 0; nt < 4; nt++) {
      bf16x8 bb = *(const bf16x8*)&Wt[(size_t)(nt * 16 + lr) * K + kt * 32 + lg * 8];
      acc[nt] = __builtin_amdgcn_mfma_f32_16x16x32_bf16(a, bb, acc[nt], 0, 0, 0);
    }
  }

  #pragma unroll
  for (int nt = 0; nt < 4; nt++) {
    int n = nt * 16 + lr;
    float bv = bias ? bias[n] : 0.f;
    #pragma unroll
    for (int r = 0; r < 4; r++) {
      int px = wid * 16 + lg * 4 + r;
      out[(size_t)(pxb + px) * 64 + n] = f2b(acc[nt][r] + bv);
    }
  }
}

__global__ __launch_bounds__(256) void emb_both_kernel(
    const float* __restrict__ fine, const unsigned short* __restrict__ Wtf,
    const float* __restrict__ fbias, unsigned short* __restrict__ femb,
    const float* __restrict__ coarse, const unsigned short* __restrict__ Wtc,
    unsigned short* __restrict__ cemb) {
  __shared__ __align__(16) unsigned short a_s[64 * 264];
  int idx = blockIdx.x;
  if (idx < Nf / 64) emb_body<128>(fine, Wtf, fbias, femb, idx * 64, a_s);
  else               emb_body<256>(coarse, Wtc, nullptr, cemb, (idx - Nf / 64) * 64, a_s);
}

// ---------------------------------------------------------------------------
// content (both): 3x3 conv 64->25 via implicit-GEMM MFMA
__global__ __launch_bounds__(256) void content_both_kernel(
    const unsigned short* __restrict__ femb, const unsigned short* __restrict__ cemb,
    const unsigned short* __restrict__ Wtcnt, const float* __restrict__ cb,
    float* __restrict__ kff, float* __restrict__ kfc) {
  constexpr int LDC = 72;
  __shared__ __align__(16) unsigned short a_s[100 * LDC];
  int idx = blockIdx.x, t = threadIdx.x;
  const unsigned short* emb;
  float* out;
  int b, i0, j0, Hd, Wd;
  if (idx < 1024) {
    b = idx >> 8; int rem = idx & 255;
    i0 = (rem >> 4) * 8; j0 = (rem & 15) * 8; Hd = 128; Wd = 128;
    emb = femb; out = kff;
  } else {
    int i2 = idx - 1024;
    b = i2 >> 6; int rem = i2 & 63;
    i0 = (rem >> 3) * 8; j0 = (rem & 7) * 8; Hd = 64; Wd = 64;
    emb = cemb; out = kfc;
  }

  for (int i = t; i < 100 * 16; i += 256) {
    int cell = i >> 4, ck = i & 15;
    int gi = i0 - 1 + cell / 10;
    int gj = j0 - 1 + cell % 10;
    short4 v = make_short4(0, 0, 0, 0);
    if (gi >= 0 && gi < Hd && gj >= 0 && gj < Wd)
      v = *(const short4*)&emb[(size_t)((b * Hd + gi) * Wd + gj) * 64 + ck * 4];
    *(short4*)&a_s[cell * LDC + ck * 4] = v;
  }
  __syncthreads();

  int wid = t >> 6, lane = t & 63;
  int lr = lane & 15, lg = lane >> 4;
  int px = wid * 16 + lr;
  int pi = px >> 3, pj = px & 7;
  const f32x4 zero4 = {0.f, 0.f, 0.f, 0.f};
  f32x4 acc[2] = {zero4, zero4};

  #pragma unroll
  for (int di = 0; di < 3; di++) {
    #pragma unroll
    for (int dj = 0; dj < 3; dj++) {
      int cell = (pi + di) * 10 + (pj + dj);
      int tap = di * 3 + dj;
      #pragma unroll
      for (int kt = 0; kt < 2; kt++) {
        bf16x8 a = *(const bf16x8*)&a_s[cell * LDC + kt * 32 + lg * 8];
        #pragma unroll
        for (int nt = 0; nt < 2; nt++) {
          bf16x8 bb = *(const bf16x8*)&Wtcnt[(size_t)(nt * 16 + lr) * 576 + tap * 64 + kt * 32 + lg * 8];
          acc[nt] = __builtin_amdgcn_mfma_f32_16x16x32_bf16(a, bb, acc[nt], 0, 0, 0);
        }
      }
    }
  }

  #pragma unroll
  for (int nt = 0; nt < 2; nt++) {
    int ch = nt * 16 + lr;
    if (ch < 25) {
      float bv = cb[ch];
      #pragma unroll
      for (int r = 0; r < 4; r++) {
        int opx = wid * 16 + lg * 4 + r;
        int gi = i0 + (opx >> 3), gj = j0 + (opx & 7);
        out[(size_t)((b * Hd + gi) * Wd + gj) * 25 + ch] = acc[nt][r] + bv;
      }
    }
  }
}

// ---------------------------------------------------------------------------
// carafe_proj: fused softmax + CARAFE(GEMM0) + dual projection + gated mix.
// No cu_g round-trip; dual GEMM has no chain (W12 precomputed).
__global__ __launch_bounds__(256, 3) void carafe_proj_kernel(
    const float* __restrict__ coarse, const float* __restrict__ kff,
    const float* __restrict__ kfc, const float* __restrict__ gatec,
    const unsigned short* __restrict__ Wt1, const float* __restrict__ b1,
    const unsigned short* __restrict__ Wt12, const float* __restrict__ b12,
    float* __restrict__ out) {
  __shared__ __align__(16) unsigned short buf[256 * 72];   // 36864 B
  __shared__ __align__(16) unsigned short m_ext[32 * 72];  // 4608 B
  __shared__ float g_s[32];
  unsigned short* win_t = buf;
  unsigned short* cu_s  = buf;

  int t = threadIdx.x;
  int b = blockIdx.z;
  int i0 = blockIdx.y * 4, j0 = blockIdx.x * 8;
  int hw0 = (i0 >> 1) - 2, ww0 = (j0 >> 1) - 2;

  // ---- phase A: stage 6x8 coarse window (thread t = channel t) + masks ----
  {
    #pragma unroll
    for (int p0 = 0; p0 < 48; p0 += 4) {
      unsigned short vals[4];
      #pragma unroll
      for (int q = 0; q < 4; q++) {
        int p = p0 + q;
        int h = hw0 + (p >> 3), w = ww0 + (p & 7);
        float v = 0.f;
        if (h >= 0 && h < 64 && w >= 0 && w < 64)
          v = coarse[(size_t)((b * 64 + h) * 64 + w) * 256 + t];
        vals[q] = f2b(v);
      }
      *(short4*)&win_t[t * 72 + p0] =
          make_short4((short)vals[0], (short)vals[1], (short)vals[2], (short)vals[3]);
    }
    short4 z4 = make_short4(0, 0, 0, 0);
    *(short4*)&win_t[t * 72 + 48] = z4;
    *(short4*)&win_t[t * 72 + 52] = z4;
    *(short4*)&win_t[t * 72 + 56] = z4;
    *(short4*)&win_t[t * 72 + 60] = z4;
  }
  if (t < 32) {
    int i = i0 + (t >> 3), j = j0 + (t & 7);
    size_t fpx = (size_t)((b * 128 + i) * 128 + j);
    size_t cpx = (size_t)((b * 64 + (i >> 1)) * 64 + (j >> 1));
    float v[25];
    float mx = -1e30f;
    #pragma unroll
    for (int m = 0; m < 25; m++) {
      v[m] = kff[fpx * 25 + m] + kfc[cpx * 25 + m];
      mx = fmaxf(mx, v[m]);
    }
    float s = 0.f;
    #pragma unroll
    for (int m = 0; m < 25; m++) { v[m] = expf(v[m] - mx); s += v[m]; }
    float inv = 1.f / s;
    unsigned* row32 = (unsigned*)&m_ext[t * 72];
    #pragma unroll
    for (int q = 0; q < 36; q++) row32[q] = 0;
    int wib = (t >> 3) >> 1, wjb = (t & 7) >> 1;
    #pragma unroll
    for (int di = 0; di < 5; di++)
      #pragma unroll
      for (int dj = 0; dj < 5; dj++)
        m_ext[t * 72 + (wib + di) * 8 + (wjb + dj)] = f2b(v[di * 5 + dj] * inv);
    g_s[t] = gatec[cpx];
  }
  __syncthreads();

  int wid = t >> 6, lane = t & 63;
  int lr = lane & 15, lg = lane >> 4;
  const f32x4 zero4 = {0.f, 0.f, 0.f, 0.f};

  // ---- GEMM0: cu[32x256] = M_ext[32x64] @ win[64x256] ----
  f32x4 acc0[2][4];
  #pragma unroll
  for (int mi = 0; mi < 2; mi++)
    #pragma unroll
    for (int ni = 0; ni < 4; ni++) acc0[mi][ni] = zero4;
  #pragma unroll
  for (int kt = 0; kt < 2; kt++) {
    bf16x8 a0 = *(const bf16x8*)&m_ext[lr * 72 + kt * 32 + lg * 8];
    bf16x8 a1 = *(const bf16x8*)&m_ext[(16 + lr) * 72 + kt * 32 + lg * 8];
    #pragma unroll
    for (int ni = 0; ni < 4; ni++) {
      bf16x8 bb = *(const bf16x8*)&win_t[(size_t)(wid * 64 + ni * 16 + lr) * 72 + kt * 32 + lg * 8];
      acc0[0][ni] = __builtin_amdgcn_mfma_f32_16x16x32_bf16(a0, bb, acc0[0][ni], 0, 0, 0);
      acc0[1][ni] = __builtin_amdgcn_mfma_f32_16x16x32_bf16(a1, bb, acc0[1][ni], 0, 0, 0);
    }
  }
  __syncthreads();  // win_t reads done; buf becomes cu_s

  #pragma unroll
  for (int mi = 0; mi < 2; mi++)
    #pragma unroll
    for (int ni = 0; ni < 4; ni++)
      #pragma unroll
      for (int r = 0; r < 4; r++)
        cu_s[(mi * 16 + lg * 4 + r) * 264 + wid * 64 + ni * 16 + lr] = f2b(acc0[mi][ni][r]);
  __syncthreads();

  // ---- dual GEMM: c_out = cu@W1+b1 ; f_out = cu@W12+b12 (independent) ----
  f32x4 accc[2][4], accf[2][4];
  #pragma unroll
  for (int mi = 0; mi < 2; mi++)
    #pragma unroll
    for (int ni = 0; ni < 4; ni++) { accc[mi][ni] = zero4; accf[mi][ni] = zero4; }
  #pragma unroll 2
  for (int kt = 0; kt < 8; kt++) {
    bf16x8 a0 = *(const bf16x8*)&cu_s[lr * 264 + kt * 32 + lg * 8];
    bf16x8 a1 = *(const bf16x8*)&cu_s[(16 + lr) * 264 + kt * 32 + lg * 8];
    #pragma unroll
    for (int ni = 0; ni < 4; ni++) {
      size_t wrow = (size_t)(wid * 64 + ni * 16 + lr) * 256 + kt * 32 + lg * 8;
      bf16x8 bc = *(const bf16x8*)&Wt1[wrow];
      bf16x8 bf = *(const bf16x8*)&Wt12[wrow];
      accc[0][ni] = __builtin_amdgcn_mfma_f32_16x16x32_bf16(a0, bc, accc[0][ni], 0, 0, 0);
      accc[1][ni] = __builtin_amdgcn_mfma_f32_16x16x32_bf16(a1, bc, accc[1][ni], 0, 0, 0);
      accf[0][ni] = __builtin_amdgcn_mfma_f32_16x16x32_bf16(a0, bf, accf[0][ni], 0, 0, 0);
      accf[1][ni] = __builtin_amdgcn_mfma_f32_16x16x32_bf16(a1, bf, accf[1][ni], 0, 0, 0);
    }
  }

  float b1v[4], b12v[4];
  #pragma unroll
  for (int ni = 0; ni < 4; ni++) {
    int n = wid * 64 + ni * 16 + lr;
    b1v[ni] = b1[n];
    b12v[ni] = b12[n];
  }

  // ---- mix + store ----
  #pragma unroll
  for (int mi = 0; mi < 2; mi++)
    #pragma unroll
    for (int ni = 0; ni < 4; ni++)
      #pragma unroll
      for (int r = 0; r < 4; r++) {
        int px = mi * 16 + lg * 4 + r;
        float g = g_s[px];
        int i = i0 + (px >> 3), j = j0 + (px & 7);
        float c_out = accc[mi][ni][r] + b1v[ni];
        float f_out = accf[mi][ni][r] + b12v[ni];
        out[(size_t)((b * 128 + i) * 128 + j) * 256 + wid * 64 + ni * 16 + lr] =
            g * f_out + (1.f - g) * c_out;
      }
}

// ---------------------------------------------------------------------------
extern "C" void kernel_launch(void* const* d_in, const int* in_sizes, int n_in,
                              void* d_out, int out_size, void* d_ws, size_t ws_size,
                              hipStream_t stream) {
  const float* fine        = (const float*)d_in[0];
  const float* coarse      = (const float*)d_in[1];
  const float* gate_w      = (const float*)d_in[2];
  const float* gate_b      = (const float*)d_in[3];
  const float* ss_fine_w   = (const float*)d_in[4];
  const float* ss_fine_b   = (const float*)d_in[5];
  const float* ss_coarse_w = (const float*)d_in[6];
  const float* ss_content_w= (const float*)d_in[7];
  const float* ss_content_b= (const float*)d_in[8];
  const float* W1          = (const float*)d_in[9];
  const float* b1          = (const float*)d_in[10];
  const float* W2          = (const float*)d_in[11];
  const float* b2          = (const float*)d_in[12];
  float* out = (float*)d_out;

  char* ws = (char*)d_ws;
  size_t off = 0;
  float* gatec = (float*)(ws + off); off += 131072;
  unsigned short* femb = (unsigned short*)(ws + off); off += (size_t)Nf * 64 * 2;
  unsigned short* cemb = (unsigned short*)(ws + off); off += (size_t)Nc * 64 * 2;
  float* kff   = (float*)(ws + off); off += (size_t)Nf * 25 * 4;
  float* kfc   = (float*)(ws + off); off += (size_t)Nc * 25 * 4;
  unsigned short* Wt1 = (unsigned short*)(ws + off); off += 65536 * 2;
  unsigned short* Wt2 = (unsigned short*)(ws + off); off += 65536 * 2;
  unsigned short* Wtf = (unsigned short*)(ws + off); off += 64 * 128 * 2;
  unsigned short* Wtc = (unsigned short*)(ws + off); off += 64 * 256 * 2;
  unsigned short* Wtcnt = (unsigned short*)(ws + off); off += 32 * 576 * 2;
  unsigned short* Wt12 = (unsigned short*)(ws + off); off += 65536 * 2;
  float* b12f = (float*)(ws + off); off += 1024;

  prep1_kernel<<<35 + Nc / 4, 256, 0, stream>>>(
      W1, W2, Wt1, Wt2, ss_fine_w, ss_coarse_w, ss_content_w, Wtf, Wtc, Wtcnt,
      coarse, gate_w, gate_b, gatec);
  prep2_kernel<<<17, 256, 0, stream>>>(W1, Wt2, Wt12, b1, W2, b2, b12f);
  emb_both_kernel<<<Nf / 64 + Nc / 64, 256, 0, stream>>>(
      fine, Wtf, ss_fine_b, femb, coarse, Wtc, cemb);
  content_both_kernel<<<1024 + 256, 256, 0, stream>>>(
      femb, cemb, Wtcnt, ss_content_b, kff, kfc);
  carafe_proj_kernel<<<dim3(Wf / 8, Hf / 4, Bb), 256, 0, stream>>>(
      coarse, kff, kfc, gatec, Wt1, b1, Wt12, b12f, out);
}

// Round 10
// 149.166 us; speedup vs baseline: 1.2387x; 1.2387x over previous
//
#include <hip/hip_runtime.h>
#include <math.h>

// Problem constants (fixed by setup_inputs)
constexpr int Bb = 4, Hc = 64, Wc = 64, Cc = 256, Cf = 128, E = 64, KK = 25, F = 256;
constexpr int Hf = 128, Wf = 128;
constexpr int Nc = Bb * Hc * Wc;   // 16384 coarse pixels
constexpr int Nf = Bb * Hf * Wf;   // 65536 fine pixels

typedef __attribute__((ext_vector_type(8))) short bf16x8;
typedef __attribute__((ext_vector_type(4))) float f32x4;

__device__ inline unsigned short f2b(float f) {
  union { float f; unsigned u; } v; v.f = f;
  return (unsigned short)((v.u + 0x7FFF + ((v.u >> 16) & 1)) >> 16);
}

// ---------------------------------------------------------------------------
// prep1: blocks 0..31 wprep (W1,W2 -> Wt1,Wt2); 32..34 sprep; 35.. gate
__global__ __launch_bounds__(256) void prep1_kernel(
    const float* __restrict__ W1, const float* __restrict__ W2,
    unsigned short* __restrict__ Wt1, unsigned short* __restrict__ Wt2,
    const float* __restrict__ fw, const float* __restrict__ cw,
    const float* __restrict__ cntw, unsigned short* __restrict__ Wtf,
    unsigned short* __restrict__ Wtc, unsigned short* __restrict__ Wtcnt,
    const float* __restrict__ coarse, const float* __restrict__ gw,
    const float* __restrict__ gb, float* __restrict__ gatec) {
  __shared__ float tile[64][65];
  int idx = blockIdx.x, t = threadIdx.x;
  if (idx < 32) {
    const float* W = (idx >= 16) ? W2 : W1;
    unsigned short* Wt = (idx >= 16) ? Wt2 : Wt1;
    int k0 = ((idx >> 2) & 3) * 64, n0 = (idx & 3) * 64;
    int r0 = t >> 6, c = t & 63;
    for (int r = r0; r < 64; r += 4)
      tile[r][c] = W[(size_t)(k0 + r) * 256 + n0 + c];
    __syncthreads();
    for (int r = r0; r < 64; r += 4)
      Wt[(size_t)(n0 + r) * 256 + k0 + c] = f2b(tile[c][r]);
  } else if (idx < 35) {
    int sec = idx - 32;
    if (sec == 0) {
      for (int i = t; i < 64 * 128; i += 256) {
        int n = i & 63, k = i >> 6;
        Wtf[n * 128 + k] = f2b(fw[k * 64 + n]);
      }
    } else if (sec == 1) {
      for (int i = t; i < 64 * 256; i += 256) {
        int n = i & 63, k = i >> 6;
        Wtc[n * 256 + k] = f2b(cw[k * 64 + n]);
      }
    } else {
      for (int i = t; i < 32 * 576; i += 256) {
        int n = i & 31, kk = i >> 5;
        Wtcnt[n * 576 + kk] = (n < 25) ? f2b(cntw[kk * 25 + n]) : (unsigned short)0;
      }
    }
  } else {
    int px = (idx - 35) * 4 + (t >> 6);
    int lane = t & 63;
    const float4 a = *(const float4*)(coarse + (size_t)px * 256 + lane * 4);
    const float4 w = *(const float4*)(gw + lane * 4);
    float v = a.x * w.x + a.y * w.y + a.z * w.z + a.w * w.w;
    #pragma unroll
    for (int off = 32; off; off >>= 1) v += __shfl_xor(v, off);
    if (lane == 0) gatec[px] = 1.f / (1.f + expf(-(v + gb[0])));
  }
}

// ---------------------------------------------------------------------------
// prep2: blocks 0..15 Wt12[n][k]=(W1@W2)^T bf16 via MFMA; block 16: b12
__global__ __launch_bounds__(256) void prep2_kernel(
    const float* __restrict__ W1, const unsigned short* __restrict__ Wt2,
    unsigned short* __restrict__ Wt12, const float* __restrict__ b1,
    const float* __restrict__ W2, const float* __restrict__ b2,
    float* __restrict__ b12f) {
  __shared__ __align__(16) unsigned short a_s[64 * 264];
  int idx = blockIdx.x, t = threadIdx.x;
  if (idx == 16) {
    int n = t;
    float acc = b2[n];
    #pragma unroll 8
    for (int m = 0; m < 256; m++) acc += b1[m] * W2[(size_t)m * 256 + n];
    b12f[n] = acc;
    return;
  }
  int nbase = (idx & 3) * 64, k0 = (idx >> 2) * 64;
  for (int i = t; i < 64 * 64; i += 256) {
    int row = i >> 6, mc = i & 63;
    float4 v = *(const float4*)&W1[(size_t)(k0 + row) * 256 + mc * 4];
    *(short4*)&a_s[row * 264 + mc * 4] =
        make_short4((short)f2b(v.x), (short)f2b(v.y), (short)f2b(v.z), (short)f2b(v.w));
  }
  __syncthreads();
  int wid = t >> 6, lane = t & 63;
  int lr = lane & 15, lg = lane >> 4;
  const f32x4 zero4 = {0.f, 0.f, 0.f, 0.f};
  f32x4 acc[4] = {zero4, zero4, zero4, zero4};
  #pragma unroll
  for (int kt = 0; kt < 8; kt++) {
    bf16x8 a = *(const bf16x8*)&a_s[(wid * 16 + lr) * 264 + kt * 32 + lg * 8];
    #pragma unroll
    for (int nt = 0; nt < 4; nt++) {
      bf16x8 bb = *(const bf16x8*)&Wt2[(size_t)(nbase + nt * 16 + lr) * 256 + kt * 32 + lg * 8];
      acc[nt] = __builtin_amdgcn_mfma_f32_16x16x32_bf16(a, bb, acc[nt], 0, 0, 0);
    }
  }
  #pragma unroll
  for (int nt = 0; nt < 4; nt++)
    #pragma unroll
    for (int r = 0; r < 4; r++)
      Wt12[(size_t)(nbase + nt * 16 + lr) * 256 + k0 + wid * 16 + lg * 4 + r] =
          f2b(acc[nt][r]);
}

// ---------------------------------------------------------------------------
// emb (both resolutions): out_bf16[px][64] = in[px][K] @ Wt[64][K]
template <int K>
__device__ inline void emb_body(const float* __restrict__ in,
                                const unsigned short* __restrict__ Wt,
                                const float* __restrict__ bias,
                                unsigned short* __restrict__ out, int pxb,
                                unsigned short* a_s) {
  constexpr int LDA = K + 8;
  int t = threadIdx.x;
  constexpr int KC = K / 4;
  for (int idx = t; idx < 64 * KC; idx += 256) {
    int px = idx / KC, kc = idx % KC;
    float4 v = *(const float4*)&in[(size_t)(pxb + px) * K + kc * 4];
    *(short4*)&a_s[px * LDA + kc * 4] =
        make_short4((short)f2b(v.x), (short)f2b(v.y), (short)f2b(v.z), (short)f2b(v.w));
  }
  __syncthreads();

  int wid = t >> 6, lane = t & 63;
  int lr = lane & 15, lg = lane >> 4;
  const f32x4 zero4 = {0.f, 0.f, 0.f, 0.f};
  f32x4 acc[4] = {zero4, zero4, zero4, zero4};

  #pragma unroll
  for (int kt = 0; kt < K / 32; kt++) {
    bf16x8 a = *(const bf16x8*)&a_s[(wid * 16 + lr) * LDA + kt * 32 + lg * 8];
    #pragma unroll
    for (int nt = 0; nt < 4; nt++) {
      bf16x8 bb = *(const bf16x8*)&Wt[(size_t)(nt * 16 + lr) * K + kt * 32 + lg * 8];
      acc[nt] = __builtin_amdgcn_mfma_f32_16x16x32_bf16(a, bb, acc[nt], 0, 0, 0);
    }
  }

  #pragma unroll
  for (int nt = 0; nt < 4; nt++) {
    int n = nt * 16 + lr;
    float bv = bias ? bias[n] : 0.f;
    #pragma unroll
    for (int r = 0; r < 4; r++) {
      int px = wid * 16 + lg * 4 + r;
      out[(size_t)(pxb + px) * 64 + n] = f2b(acc[nt][r] + bv);
    }
  }
}

__global__ __launch_bounds__(256) void emb_both_kernel(
    const float* __restrict__ fine, const unsigned short* __restrict__ Wtf,
    const float* __restrict__ fbias, unsigned short* __restrict__ femb,
    const float* __restrict__ coarse, const unsigned short* __restrict__ Wtc,
    unsigned short* __restrict__ cemb) {
  __shared__ __align__(16) unsigned short a_s[64 * 264];
  int idx = blockIdx.x;
  if (idx < Nf / 64) emb_body<128>(fine, Wtf, fbias, femb, idx * 64, a_s);
  else               emb_body<256>(coarse, Wtc, nullptr, cemb, (idx - Nf / 64) * 64, a_s);
}

// ---------------------------------------------------------------------------
// content (both): 3x3 conv 64->25 via implicit-GEMM MFMA
__global__ __launch_bounds__(256) void content_both_kernel(
    const unsigned short* __restrict__ femb, const unsigned short* __restrict__ cemb,
    const unsigned short* __restrict__ Wtcnt, const float* __restrict__ cb,
    float* __restrict__ kff, float* __restrict__ kfc) {
  constexpr int LDC = 72;
  __shared__ __align__(16) unsigned short a_s[100 * LDC];
  int idx = blockIdx.x, t = threadIdx.x;
  const unsigned short* emb;
  float* out;
  int b, i0, j0, Hd, Wd;
  if (idx < 1024) {
    b = idx >> 8; int rem = idx & 255;
    i0 = (rem >> 4) * 8; j0 = (rem & 15) * 8; Hd = 128; Wd = 128;
    emb = femb; out = kff;
  } else {
    int i2 = idx - 1024;
    b = i2 >> 6; int rem = i2 & 63;
    i0 = (rem >> 3) * 8; j0 = (rem & 7) * 8; Hd = 64; Wd = 64;
    emb = cemb; out = kfc;
  }

  for (int i = t; i < 100 * 16; i += 256) {
    int cell = i >> 4, ck = i & 15;
    int gi = i0 - 1 + cell / 10;
    int gj = j0 - 1 + cell % 10;
    short4 v = make_short4(0, 0, 0, 0);
    if (gi >= 0 && gi < Hd && gj >= 0 && gj < Wd)
      v = *(const short4*)&emb[(size_t)((b * Hd + gi) * Wd + gj) * 64 + ck * 4];
    *(short4*)&a_s[cell * LDC + ck * 4] = v;
  }
  __syncthreads();

  int wid = t >> 6, lane = t & 63;
  int lr = lane & 15, lg = lane >> 4;
  int px = wid * 16 + lr;
  int pi = px >> 3, pj = px & 7;
  const f32x4 zero4 = {0.f, 0.f, 0.f, 0.f};
  f32x4 acc[2] = {zero4, zero4};

  #pragma unroll
  for (int di = 0; di < 3; di++) {
    #pragma unroll
    for (int dj = 0; dj < 3; dj++) {
      int cell = (pi + di) * 10 + (pj + dj);
      int tap = di * 3 + dj;
      #pragma unroll
      for (int kt = 0; kt < 2; kt++) {
        bf16x8 a = *(const bf16x8*)&a_s[cell * LDC + kt * 32 + lg * 8];
        #pragma unroll
        for (int nt = 0; nt < 2; nt++) {
          bf16x8 bb = *(const bf16x8*)&Wtcnt[(size_t)(nt * 16 + lr) * 576 + tap * 64 + kt * 32 + lg * 8];
          acc[nt] = __builtin_amdgcn_mfma_f32_16x16x32_bf16(a, bb, acc[nt], 0, 0, 0);
        }
      }
    }
  }

  #pragma unroll
  for (int nt = 0; nt < 2; nt++) {
    int ch = nt * 16 + lr;
    if (ch < 25) {
      float bv = cb[ch];
      #pragma unroll
      for (int r = 0; r < 4; r++) {
        int opx = wid * 16 + lg * 4 + r;
        int gi = i0 + (opx >> 3), gj = j0 + (opx & 7);
        out[(size_t)((b * Hd + gi) * Wd + gj) * 25 + ch] = acc[nt][r] + bv;
      }
    }
  }
}

// ---------------------------------------------------------------------------
// carafe (64 px / block): 8x8 fine tile -> 8x8 coarse window (all 64 taps
// used, no zero padding). cu_g bf16 [Nf][256].
__global__ __launch_bounds__(256) void carafe_kernel(
    const float* __restrict__ coarse, const float* __restrict__ kff,
    const float* __restrict__ kfc, unsigned short* __restrict__ cu_g) {
  __shared__ __align__(16) unsigned short buf[256 * 72];   // win_t, then cu_s
  __shared__ __align__(16) unsigned short m_ext[64 * 72];  // 9216 B
  unsigned short* win_t = buf;
  unsigned short* cu_s  = buf;

  int t = threadIdx.x;
  int b = blockIdx.z;
  int i0 = blockIdx.y * 8, j0 = blockIdx.x * 8;
  int hw0 = (i0 >> 1) - 2, ww0 = (j0 >> 1) - 2;

  // ---- stage 8x8 coarse window: thread t = channel t, 64 taps ----
  {
    #pragma unroll
    for (int p0 = 0; p0 < 64; p0 += 4) {
      unsigned short vals[4];
      #pragma unroll
      for (int q = 0; q < 4; q++) {
        int p = p0 + q;
        int h = hw0 + (p >> 3), w = ww0 + (p & 7);
        float v = 0.f;
        if (h >= 0 && h < 64 && w >= 0 && w < 64)
          v = coarse[(size_t)((b * 64 + h) * 64 + w) * 256 + t];
        vals[q] = f2b(v);
      }
      *(short4*)&win_t[t * 72 + p0] =
          make_short4((short)vals[0], (short)vals[1], (short)vals[2], (short)vals[3]);
    }
  }
  // ---- masks: thread t<64 owns fine px (i0 + t>>3, j0 + (t&7)) ----
  if (t < 64) {
    int ti = t >> 3, tj = t & 7;
    int i = i0 + ti, j = j0 + tj;
    size_t fpx = (size_t)((b * 128 + i) * 128 + j);
    size_t cpx = (size_t)((b * 64 + (i >> 1)) * 64 + (j >> 1));
    float v[25];
    float mx = -1e30f;
    #pragma unroll
    for (int m = 0; m < 25; m++) {
      v[m] = kff[fpx * 25 + m] + kfc[cpx * 25 + m];
      mx = fmaxf(mx, v[m]);
    }
    float s = 0.f;
    #pragma unroll
    for (int m = 0; m < 25; m++) { v[m] = expf(v[m] - mx); s += v[m]; }
    float inv = 1.f / s;
    unsigned* row32 = (unsigned*)&m_ext[t * 72];
    #pragma unroll
    for (int q = 0; q < 36; q++) row32[q] = 0;
    int wib = ti >> 1, wjb = tj >> 1;   // 0..3
    #pragma unroll
    for (int di = 0; di < 5; di++)
      #pragma unroll
      for (int dj = 0; dj < 5; dj++)
        m_ext[t * 72 + (wib + di) * 8 + (wjb + dj)] = f2b(v[di * 5 + dj] * inv);
  }
  __syncthreads();

  int wid = t >> 6, lane = t & 63;
  int lr = lane & 15, lg = lane >> 4;
  const f32x4 zero4 = {0.f, 0.f, 0.f, 0.f};

  // ---- GEMM0: cu[64x256] = M_ext[64x64] @ win[64x256] ----
  f32x4 acc0[4][4];
  #pragma unroll
  for (int mi = 0; mi < 4; mi++)
    #pragma unroll
    for (int ni = 0; ni < 4; ni++) acc0[mi][ni] = zero4;
  #pragma unroll
  for (int kt = 0; kt < 2; kt++) {
    bf16x8 am[4];
    #pragma unroll
    for (int mi = 0; mi < 4; mi++)
      am[mi] = *(const bf16x8*)&m_ext[(mi * 16 + lr) * 72 + kt * 32 + lg * 8];
    #pragma unroll
    for (int ni = 0; ni < 4; ni++) {
      bf16x8 bb = *(const bf16x8*)&win_t[(size_t)(wid * 64 + ni * 16 + lr) * 72 + kt * 32 + lg * 8];
      #pragma unroll
      for (int mi = 0; mi < 4; mi++)
        acc0[mi][ni] = __builtin_amdgcn_mfma_f32_16x16x32_bf16(am[mi], bb, acc0[mi][ni], 0, 0, 0);
    }
  }
  __syncthreads();  // win_t reads done; buf becomes cu_s

  #pragma unroll
  for (int mi = 0; mi < 4; mi++)
    #pragma unroll
    for (int ni = 0; ni < 4; ni++)
      #pragma unroll
      for (int r = 0; r < 4; r++)
        cu_s[(mi * 16 + lg * 4 + r) * 264 + wid * 64 + ni * 16 + lr] = f2b(acc0[mi][ni][r]);
  __syncthreads();

  // ---- coalesced copy LDS -> global (64 px x 256 ch bf16) ----
  for (int c = t; c < 2048; c += 256) {
    int p = c >> 5, off = (c & 31) << 3;
    int gi = i0 + (p >> 3), gj = j0 + (p & 7);
    bf16x8 v = *(const bf16x8*)&cu_s[p * 264 + off];
    *(bf16x8*)&cu_g[(size_t)((b * 128 + gi) * 128 + gj) * 256 + off] = v;
  }
}

// ---------------------------------------------------------------------------
// proj: persistent 4-tile pipeline, weights in regs, LDS double buffer.
// Grid 1024: bid = cg*256 + g (cg slow -> tile-sharing blocks on same XCD).
__global__ __launch_bounds__(256, 2) void proj_kernel(
    const unsigned short* __restrict__ cu_g, const float* __restrict__ gatec,
    const unsigned short* __restrict__ Wt1, const float* __restrict__ b1,
    const unsigned short* __restrict__ Wt12, const float* __restrict__ b12,
    float* __restrict__ out) {
  __shared__ __align__(16) unsigned short a_s[2][64 * 264];  // 2 x 33792 B
  __shared__ float g_s[2][32];
  int t = threadIdx.x;
  int bid = blockIdx.x;
  int cg = bid >> 8;      // 0..3 (slow)
  int g  = bid & 255;     // 0..255
  int wid = t >> 6, lane = t & 63;
  int lr = lane & 15, lg = lane >> 4;
  int n0 = cg * 64 + wid * 16;

  // preload this wave's dual B-fragments (whole-block lifetime)
  bf16x8 wb1[8], wb12[8];
  #pragma unroll
  for (int kt = 0; kt < 8; kt++) {
    size_t wrow = (size_t)(n0 + lr) * 256 + kt * 32 + lg * 8;
    wb1[kt]  = *(const bf16x8*)&Wt1[wrow];
    wb12[kt] = *(const bf16x8*)&Wt12[wrow];
  }
  float b1v  = b1[n0 + lr];
  float b12v = b12[n0 + lr];

  // prologue: stage tile 0 into buf 0
  {
    size_t m0 = (size_t)g * 256;  // (g*4+0)*64
    for (int c = t; c < 2048; c += 256) {
      int row = c >> 5, off = (c & 31) << 3;
      *(bf16x8*)&a_s[0][row * 264 + off] = *(const bf16x8*)&cu_g[(m0 + row) * 256 + off];
    }
    if (t < 32) {
      int b_ = (int)(m0 >> 14), ii = (int)((m0 >> 7) & 127), j0 = (int)(m0 & 127);
      g_s[0][t] = gatec[(size_t)(b_ * 64 + (ii >> 1)) * 64 + (j0 >> 1) + t];
    }
  }
  __syncthreads();

  const f32x4 zero4 = {0.f, 0.f, 0.f, 0.f};

  for (int it = 0; it < 4; ++it) {
    int cur = it & 1, nxt = cur ^ 1;
    size_t m0i = (size_t)(g * 4 + it) * 64;

    // 1. issue prefetch of next tile into regs (overlaps MFMA below)
    bf16x8 pf[8];
    float gpf = 0.f;
    if (it < 3) {
      size_t m0n = m0i + 64;
      #pragma unroll
      for (int q = 0; q < 8; q++) {
        int c = t + q * 256;
        int row = c >> 5, off = (c & 31) << 3;
        pf[q] = *(const bf16x8*)&cu_g[(m0n + row) * 256 + off];
      }
      if (t < 32) {
        int b_ = (int)(m0n >> 14), ii = (int)((m0n >> 7) & 127), j0 = (int)(m0n & 127);
        gpf = gatec[(size_t)(b_ * 64 + (ii >> 1)) * 64 + (j0 >> 1) + t];
      }
    }

    // 2. dual MFMA on current buffer
    f32x4 accc[4] = {zero4, zero4, zero4, zero4};
    f32x4 accf[4] = {zero4, zero4, zero4, zero4};
    #pragma unroll
    for (int kt = 0; kt < 8; kt++) {
      #pragma unroll
      for (int mi = 0; mi < 4; mi++) {
        bf16x8 a = *(const bf16x8*)&a_s[cur][(mi * 16 + lr) * 264 + kt * 32 + lg * 8];
        accc[mi] = __builtin_amdgcn_mfma_f32_16x16x32_bf16(a, wb1[kt],  accc[mi], 0, 0, 0);
        accf[mi] = __builtin_amdgcn_mfma_f32_16x16x32_bf16(a, wb12[kt], accf[mi], 0, 0, 0);
      }
    }

    // 3. write prefetched tile into other buffer
    if (it < 3) {
      #pragma unroll
      for (int q = 0; q < 8; q++) {
        int c = t + q * 256;
        int row = c >> 5, off = (c & 31) << 3;
        *(bf16x8*)&a_s[nxt][row * 264 + off] = pf[q];
      }
      if (t < 32) g_s[nxt][t] = gpf;
    }

    // 4. mix + store current tile
    #pragma unroll
    for (int mi = 0; mi < 4; mi++) {
      #pragma unroll
      for (int r = 0; r < 4; r++) {
        int row = mi * 16 + lg * 4 + r;
        float gg = g_s[cur][row >> 1];
        float f_out = accf[mi][r] + b12v;
        float c_out = accc[mi][r] + b1v;
        out[(m0i + row) * 256 + n0 + lr] = gg * f_out + (1.f - gg) * c_out;
      }
    }

    // 5. one barrier per iteration
    if (it < 3) __syncthreads();
  }
}

// ---------------------------------------------------------------------------
extern "C" void kernel_launch(void* const* d_in, const int* in_sizes, int n_in,
                              void* d_out, int out_size, void* d_ws, size_t ws_size,
                              hipStream_t stream) {
  const float* fine        = (const float*)d_in[0];
  const float* coarse      = (const float*)d_in[1];
  const float* gate_w      = (const float*)d_in[2];
  const float* gate_b      = (const float*)d_in[3];
  const float* ss_fine_w   = (const float*)d_in[4];
  const float* ss_fine_b   = (const float*)d_in[5];
  const float* ss_coarse_w = (const float*)d_in[6];
  const float* ss_content_w= (const float*)d_in[7];
  const float* ss_content_b= (const float*)d_in[8];
  const float* W1          = (const float*)d_in[9];
  const float* b1          = (const float*)d_in[10];
  const float* W2          = (const float*)d_in[11];
  const float* b2          = (const float*)d_in[12];
  float* out = (float*)d_out;

  char* ws = (char*)d_ws;
  size_t off = 0;
  float* gatec = (float*)(ws + off); off += 131072;
  unsigned short* femb = (unsigned short*)(ws + off); off += (size_t)Nf * 64 * 2;
  unsigned short* cemb = (unsigned short*)(ws + off); off += (size_t)Nc * 64 * 2;
  float* kff   = (float*)(ws + off); off += (size_t)Nf * 25 * 4;
  float* kfc   = (float*)(ws + off); off += (size_t)Nc * 25 * 4;
  unsigned short* Wt1 = (unsigned short*)(ws + off); off += 65536 * 2;
  unsigned short* Wt2 = (unsigned short*)(ws + off); off += 65536 * 2;
  unsigned short* Wtf = (unsigned short*)(ws + off); off += 64 * 128 * 2;
  unsigned short* Wtc = (unsigned short*)(ws + off); off += 64 * 256 * 2;
  unsigned short* Wtcnt = (unsigned short*)(ws + off); off += 32 * 576 * 2;
  unsigned short* Wt12 = (unsigned short*)(ws + off); off += 65536 * 2;
  float* b12f = (float*)(ws + off); off += 1024;
  unsigned short* cu_g = (unsigned short*)(ws + off); off += (size_t)Nf * 256 * 2;

  prep1_kernel<<<35 + Nc / 4, 256, 0, stream>>>(
      W1, W2, Wt1, Wt2, ss_fine_w, ss_coarse_w, ss_content_w, Wtf, Wtc, Wtcnt,
      coarse, gate_w, gate_b, gatec);
  prep2_kernel<<<17, 256, 0, stream>>>(W1, Wt2, Wt12, b1, W2, b2, b12f);
  emb_both_kernel<<<Nf / 64 + Nc / 64, 256, 0, stream>>>(
      fine, Wtf, ss_fine_b, femb, coarse, Wtc, cemb);
  content_both_kernel<<<1024 + 256, 256, 0, stream>>>(
      femb, cemb, Wtcnt, ss_content_b, kff, kfc);
  carafe_kernel<<<dim3(Wf / 8, Hf / 8, Bb), 256, 0, stream>>>(coarse, kff, kfc, cu_g);
  proj_kernel<<<1024, 256, 0, stream>>>(cu_g, gatec, Wt1, b1, Wt12, b12f, out);
}

// Round 11
// 148.828 us; speedup vs baseline: 1.2415x; 1.0023x over previous
//
#include <hip/hip_runtime.h>
#include <math.h>

// Problem constants (fixed by setup_inputs)
constexpr int Bb = 4, Hc = 64, Wc = 64, Cc = 256, Cf = 128, E = 64, KK = 25, F = 256;
constexpr int Hf = 128, Wf = 128;
constexpr int Nc = Bb * Hc * Wc;   // 16384 coarse pixels
constexpr int Nf = Bb * Hf * Wf;   // 65536 fine pixels

typedef __attribute__((ext_vector_type(8))) short bf16x8;
typedef __attribute__((ext_vector_type(4))) float f32x4;

__device__ inline unsigned short f2b(float f) {
  union { float f; unsigned u; } v; v.f = f;
  return (unsigned short)((v.u + 0x7FFF + ((v.u >> 16) & 1)) >> 16);
}

// ---------------------------------------------------------------------------
// prep: 0..15 Wt1 transpose; 16..18 sprep; 19..34 W12 (self-contained);
//       35 b12; 36.. gate
__global__ __launch_bounds__(256) void prep_kernel(
    const float* __restrict__ W1, const float* __restrict__ W2,
    unsigned short* __restrict__ Wt1, unsigned short* __restrict__ Wt12,
    float* __restrict__ b12f, const float* __restrict__ b1,
    const float* __restrict__ b2,
    const float* __restrict__ fw, const float* __restrict__ cw,
    const float* __restrict__ cntw, unsigned short* __restrict__ Wtf,
    unsigned short* __restrict__ Wtc, unsigned short* __restrict__ Wtcnt,
    const float* __restrict__ coarse, const float* __restrict__ gw,
    const float* __restrict__ gb, float* __restrict__ gatec) {
  __shared__ __align__(16) char smem[64 * 72 * 2 * 2];  // 18432 B shared pool
  int idx = blockIdx.x, t = threadIdx.x;

  if (idx < 16) {
    // ---- Wt1[n][k] = bf16(W1[k][n]) ----
    float (*tile)[65] = (float(*)[65])smem;             // 16640 B < 18432
    int k0 = ((idx >> 2) & 3) * 64, n0 = (idx & 3) * 64;
    int r0 = t >> 6, c = t & 63;
    for (int r = r0; r < 64; r += 4)
      tile[r][c] = W1[(size_t)(k0 + r) * 256 + n0 + c];
    __syncthreads();
    for (int r = r0; r < 64; r += 4)
      Wt1[(size_t)(n0 + r) * 256 + k0 + c] = f2b(tile[c][r]);
  } else if (idx < 19) {
    int sec = idx - 16;
    if (sec == 0) {
      for (int i = t; i < 64 * 128; i += 256) {
        int n = i & 63, k = i >> 6;
        Wtf[n * 128 + k] = f2b(fw[k * 64 + n]);
      }
    } else if (sec == 1) {
      for (int i = t; i < 64 * 256; i += 256) {
        int n = i & 63, k = i >> 6;
        Wtc[n * 256 + k] = f2b(cw[k * 64 + n]);
      }
    } else {
      for (int i = t; i < 32 * 576; i += 256) {
        int n = i & 31, kk = i >> 5;
        Wtcnt[n * 576 + kk] = (n < 25) ? f2b(cntw[kk * 25 + n]) : (unsigned short)0;
      }
    }
  } else if (idx < 35) {
    // ---- Wt12[n][k] = bf16((W1@W2)[k][n]) via MFMA, self-contained ----
    unsigned short* a_s = (unsigned short*)smem;            // [64*72]
    unsigned short* b_s = (unsigned short*)smem + 64 * 72;  // [64*72]
    int sub = idx - 19;
    int nbase = (sub & 3) * 64, k0 = (sub >> 2) * 64;
    int wid = t >> 6, lane = t & 63;
    int lr = lane & 15, lg = lane >> 4;
    const f32x4 zero4 = {0.f, 0.f, 0.f, 0.f};
    f32x4 acc[4] = {zero4, zero4, zero4, zero4};

    for (int mc = 0; mc < 4; mc++) {
      // A: W1[k0+r][mc*64 + c]  (coalesced read, linear LDS write)
      for (int i = t; i < 64 * 16; i += 256) {
        int r = i >> 4, c4 = i & 15;
        float4 v = *(const float4*)&W1[(size_t)(k0 + r) * 256 + mc * 64 + c4 * 4];
        *(short4*)&a_s[r * 72 + c4 * 4] =
            make_short4((short)f2b(v.x), (short)f2b(v.y), (short)f2b(v.z), (short)f2b(v.w));
      }
      // B^T: b_s[n][m] = W2[mc*64+m][n0+n]  (coalesced read, scatter write)
      for (int i = t; i < 64 * 16; i += 256) {
        int m = i >> 4, n4 = i & 15;
        float4 v = *(const float4*)&W2[(size_t)(mc * 64 + m) * 256 + nbase + n4 * 4];
        b_s[(n4 * 4 + 0) * 72 + m] = f2b(v.x);
        b_s[(n4 * 4 + 1) * 72 + m] = f2b(v.y);
        b_s[(n4 * 4 + 2) * 72 + m] = f2b(v.z);
        b_s[(n4 * 4 + 3) * 72 + m] = f2b(v.w);
      }
      __syncthreads();
      #pragma unroll
      for (int kt = 0; kt < 2; kt++) {
        bf16x8 a = *(const bf16x8*)&a_s[(wid * 16 + lr) * 72 + kt * 32 + lg * 8];
        #pragma unroll
        for (int nt = 0; nt < 4; nt++) {
          bf16x8 bb = *(const bf16x8*)&b_s[(nt * 16 + lr) * 72 + kt * 32 + lg * 8];
          acc[nt] = __builtin_amdgcn_mfma_f32_16x16x32_bf16(a, bb, acc[nt], 0, 0, 0);
        }
      }
      __syncthreads();
    }
    #pragma unroll
    for (int nt = 0; nt < 4; nt++)
      #pragma unroll
      for (int r = 0; r < 4; r++)
        Wt12[(size_t)(nbase + nt * 16 + lr) * 256 + k0 + wid * 16 + lg * 4 + r] =
            f2b(acc[nt][r]);
  } else if (idx == 35) {
    int n = t;
    float acc = b2[n];
    #pragma unroll 8
    for (int m = 0; m < 256; m++) acc += b1[m] * W2[(size_t)m * 256 + n];
    b12f[n] = acc;
  } else {
    int px = (idx - 36) * 4 + (t >> 6);
    int lane = t & 63;
    const float4 a = *(const float4*)(coarse + (size_t)px * 256 + lane * 4);
    const float4 w = *(const float4*)(gw + lane * 4);
    float v = a.x * w.x + a.y * w.y + a.z * w.z + a.w * w.w;
    #pragma unroll
    for (int off = 32; off; off >>= 1) v += __shfl_xor(v, off);
    if (lane == 0) gatec[px] = 1.f / (1.f + expf(-(v + gb[0])));
  }
}

// ---------------------------------------------------------------------------
// embcontent: fused 1x1 embedding (on 10x10 halo, in LDS) + 3x3 content conv.
// Per block: 8x8 output tile. femb/cemb never touch global memory.
template <int K>
__device__ inline void embcontent_body(
    const float* __restrict__ in, const unsigned short* __restrict__ Wt,
    const float* __restrict__ ebias, const unsigned short* __restrict__ Wtcnt,
    const float* __restrict__ cb, float* __restrict__ out,
    int b, int i0, int j0, int Hd, int Wd,
    unsigned short* in_s /*[112*136]*/, unsigned short* emb_s /*[112*72]*/) {
  int t = threadIdx.x;
  int wid = t >> 6, lane = t & 63;
  int lr = lane & 15, lg = lane >> 4;
  const f32x4 zero4 = {0.f, 0.f, 0.f, 0.f};

  // ---- emb phase: 112 rows (100 live), wave wid owns M-tiles {wid, wid+4} ----
  f32x4 eacc[2][4];
  #pragma unroll
  for (int mi = 0; mi < 2; mi++)
    #pragma unroll
    for (int nt = 0; nt < 4; nt++) eacc[mi][nt] = zero4;

  #pragma unroll
  for (int ch = 0; ch < K; ch += 128) {
    // stage 100-cell halo x 128ch chunk (f32 -> bf16)
    for (int i = t; i < 100 * 32; i += 256) {
      int cell = i >> 5, kc = i & 31;
      int gi = i0 - 1 + cell / 10;
      int gj = j0 - 1 + cell % 10;
      short4 v4 = make_short4(0, 0, 0, 0);
      if (gi >= 0 && gi < Hd && gj >= 0 && gj < Wd) {
        float4 v = *(const float4*)&in[(size_t)((b * Hd + gi) * Wd + gj) * K + ch + kc * 4];
        v4 = make_short4((short)f2b(v.x), (short)f2b(v.y), (short)f2b(v.z), (short)f2b(v.w));
      }
      *(short4*)&in_s[cell * 136 + kc * 4] = v4;
    }
    __syncthreads();
    #pragma unroll
    for (int kt = 0; kt < 4; kt++) {
      #pragma unroll
      for (int mi = 0; mi < 2; mi++) {
        int tile = wid + mi * 4;
        if (tile < 7) {
          bf16x8 a = *(const bf16x8*)&in_s[(tile * 16 + lr) * 136 + kt * 32 + lg * 8];
          #pragma unroll
          for (int nt = 0; nt < 4; nt++) {
            bf16x8 bb = *(const bf16x8*)&Wt[(size_t)(nt * 16 + lr) * K + ch + kt * 32 + lg * 8];
            eacc[mi][nt] = __builtin_amdgcn_mfma_f32_16x16x32_bf16(a, bb, eacc[mi][nt], 0, 0, 0);
          }
        }
      }
    }
    __syncthreads();  // in_s reads done before restage (K=256) / emb_s write
  }

  // write emb to LDS
  #pragma unroll
  for (int mi = 0; mi < 2; mi++) {
    int tile = wid + mi * 4;
    if (tile < 7) {
      #pragma unroll
      for (int nt = 0; nt < 4; nt++) {
        int n = nt * 16 + lr;
        float bv = ebias ? ebias[n] : 0.f;
        #pragma unroll
        for (int r = 0; r < 4; r++)
          emb_s[(tile * 16 + lg * 4 + r) * 72 + n] = f2b(eacc[mi][nt][r] + bv);
      }
    }
  }
  __syncthreads();

  // ---- content phase: 3x3 conv from emb_s ----
  int px = wid * 16 + lr;
  int pi = px >> 3, pj = px & 7;
  f32x4 acc[2] = {zero4, zero4};
  #pragma unroll
  for (int di = 0; di < 3; di++) {
    #pragma unroll
    for (int dj = 0; dj < 3; dj++) {
      int cell = (pi + di) * 10 + (pj + dj);
      int tap = di * 3 + dj;
      #pragma unroll
      for (int kt = 0; kt < 2; kt++) {
        bf16x8 a = *(const bf16x8*)&emb_s[cell * 72 + kt * 32 + lg * 8];
        #pragma unroll
        for (int nt = 0; nt < 2; nt++) {
          bf16x8 bb = *(const bf16x8*)&Wtcnt[(size_t)(nt * 16 + lr) * 576 + tap * 64 + kt * 32 + lg * 8];
          acc[nt] = __builtin_amdgcn_mfma_f32_16x16x32_bf16(a, bb, acc[nt], 0, 0, 0);
        }
      }
    }
  }
  #pragma unroll
  for (int nt = 0; nt < 2; nt++) {
    int ch = nt * 16 + lr;
    if (ch < 25) {
      float bv = cb[ch];
      #pragma unroll
      for (int r = 0; r < 4; r++) {
        int opx = wid * 16 + lg * 4 + r;
        int gi = i0 + (opx >> 3), gj = j0 + (opx & 7);
        out[(size_t)((b * Hd + gi) * Wd + gj) * 25 + ch] = acc[nt][r] + bv;
      }
    }
  }
}

__global__ __launch_bounds__(256) void embcontent_kernel(
    const float* __restrict__ fine, const unsigned short* __restrict__ Wtf,
    const float* __restrict__ fbias, const float* __restrict__ coarse,
    const unsigned short* __restrict__ Wtc, const unsigned short* __restrict__ Wtcnt,
    const float* __restrict__ cb, float* __restrict__ kff, float* __restrict__ kfc) {
  __shared__ __align__(16) unsigned short in_s[112 * 136];  // 30464 B
  __shared__ __align__(16) unsigned short emb_s[112 * 72];  // 16128 B
  int idx = blockIdx.x;
  if (idx < 1024) {
    int b = idx >> 8, rem = idx & 255;
    embcontent_body<128>(fine, Wtf, fbias, Wtcnt, cb, kff,
                         b, (rem >> 4) * 8, (rem & 15) * 8, 128, 128, in_s, emb_s);
  } else {
    int i2 = idx - 1024;
    int b = i2 >> 6, rem = i2 & 63;
    embcontent_body<256>(coarse, Wtc, nullptr, Wtcnt, cb, kfc,
                         b, (rem >> 3) * 8, (rem & 7) * 8, 64, 64, in_s, emb_s);
  }
}

// ---------------------------------------------------------------------------
// carafe (64 px / block): 8x8 fine tile -> 8x8 coarse window. cu_g bf16.
__global__ __launch_bounds__(256) void carafe_kernel(
    const float* __restrict__ coarse, const float* __restrict__ kff,
    const float* __restrict__ kfc, unsigned short* __restrict__ cu_g) {
  __shared__ __align__(16) unsigned short buf[256 * 72];   // win_t, then cu_s
  __shared__ __align__(16) unsigned short m_ext[64 * 72];  // 9216 B
  unsigned short* win_t = buf;
  unsigned short* cu_s  = buf;

  int t = threadIdx.x;
  int b = blockIdx.z;
  int i0 = blockIdx.y * 8, j0 = blockIdx.x * 8;
  int hw0 = (i0 >> 1) - 2, ww0 = (j0 >> 1) - 2;

  {
    #pragma unroll
    for (int p0 = 0; p0 < 64; p0 += 4) {
      unsigned short vals[4];
      #pragma unroll
      for (int q = 0; q < 4; q++) {
        int p = p0 + q;
        int h = hw0 + (p >> 3), w = ww0 + (p & 7);
        float v = 0.f;
        if (h >= 0 && h < 64 && w >= 0 && w < 64)
          v = coarse[(size_t)((b * 64 + h) * 64 + w) * 256 + t];
        vals[q] = f2b(v);
      }
      *(short4*)&win_t[t * 72 + p0] =
          make_short4((short)vals[0], (short)vals[1], (short)vals[2], (short)vals[3]);
    }
  }
  if (t < 64) {
    int ti = t >> 3, tj = t & 7;
    int i = i0 + ti, j = j0 + tj;
    size_t fpx = (size_t)((b * 128 + i) * 128 + j);
    size_t cpx = (size_t)((b * 64 + (i >> 1)) * 64 + (j >> 1));
    float v[25];
    float mx = -1e30f;
    #pragma unroll
    for (int m = 0; m < 25; m++) {
      v[m] = kff[fpx * 25 + m] + kfc[cpx * 25 + m];
      mx = fmaxf(mx, v[m]);
    }
    float s = 0.f;
    #pragma unroll
    for (int m = 0; m < 25; m++) { v[m] = expf(v[m] - mx); s += v[m]; }
    float inv = 1.f / s;
    unsigned* row32 = (unsigned*)&m_ext[t * 72];
    #pragma unroll
    for (int q = 0; q < 36; q++) row32[q] = 0;
    int wib = ti >> 1, wjb = tj >> 1;
    #pragma unroll
    for (int di = 0; di < 5; di++)
      #pragma unroll
      for (int dj = 0; dj < 5; dj++)
        m_ext[t * 72 + (wib + di) * 8 + (wjb + dj)] = f2b(v[di * 5 + dj] * inv);
  }
  __syncthreads();

  int wid = t >> 6, lane = t & 63;
  int lr = lane & 15, lg = lane >> 4;
  const f32x4 zero4 = {0.f, 0.f, 0.f, 0.f};

  f32x4 acc0[4][4];
  #pragma unroll
  for (int mi = 0; mi < 4; mi++)
    #pragma unroll
    for (int ni = 0; ni < 4; ni++) acc0[mi][ni] = zero4;
  #pragma unroll
  for (int kt = 0; kt < 2; kt++) {
    bf16x8 am[4];
    #pragma unroll
    for (int mi = 0; mi < 4; mi++)
      am[mi] = *(const bf16x8*)&m_ext[(mi * 16 + lr) * 72 + kt * 32 + lg * 8];
    #pragma unroll
    for (int ni = 0; ni < 4; ni++) {
      bf16x8 bb = *(const bf16x8*)&win_t[(size_t)(wid * 64 + ni * 16 + lr) * 72 + kt * 32 + lg * 8];
      #pragma unroll
      for (int mi = 0; mi < 4; mi++)
        acc0[mi][ni] = __builtin_amdgcn_mfma_f32_16x16x32_bf16(am[mi], bb, acc0[mi][ni], 0, 0, 0);
    }
  }
  __syncthreads();

  #pragma unroll
  for (int mi = 0; mi < 4; mi++)
    #pragma unroll
    for (int ni = 0; ni < 4; ni++)
      #pragma unroll
      for (int r = 0; r < 4; r++)
        cu_s[(mi * 16 + lg * 4 + r) * 264 + wid * 64 + ni * 16 + lr] = f2b(acc0[mi][ni][r]);
  __syncthreads();

  for (int c = t; c < 2048; c += 256) {
    int p = c >> 5, off = (c & 31) << 3;
    int gi = i0 + (p >> 3), gj = j0 + (p & 7);
    bf16x8 v = *(const bf16x8*)&cu_s[p * 264 + off];
    *(bf16x8*)&cu_g[(size_t)((b * 128 + gi) * 128 + gj) * 256 + off] = v;
  }
}

// ---------------------------------------------------------------------------
// proj: persistent 4-tile pipeline, weights in regs, LDS double buffer.
__global__ __launch_bounds__(256, 2) void proj_kernel(
    const unsigned short* __restrict__ cu_g, const float* __restrict__ gatec,
    const unsigned short* __restrict__ Wt1, const float* __restrict__ b1,
    const unsigned short* __restrict__ Wt12, const float* __restrict__ b12,
    float* __restrict__ out) {
  __shared__ __align__(16) unsigned short a_s[2][64 * 264];
  __shared__ float g_s[2][32];
  int t = threadIdx.x;
  int bid = blockIdx.x;
  int cg = bid >> 8;
  int g  = bid & 255;
  int wid = t >> 6, lane = t & 63;
  int lr = lane & 15, lg = lane >> 4;
  int n0 = cg * 64 + wid * 16;

  bf16x8 wb1[8], wb12[8];
  #pragma unroll
  for (int kt = 0; kt < 8; kt++) {
    size_t wrow = (size_t)(n0 + lr) * 256 + kt * 32 + lg * 8;
    wb1[kt]  = *(const bf16x8*)&Wt1[wrow];
    wb12[kt] = *(const bf16x8*)&Wt12[wrow];
  }
  float b1v  = b1[n0 + lr];
  float b12v = b12[n0 + lr];

  {
    size_t m0 = (size_t)g * 256;
    for (int c = t; c < 2048; c += 256) {
      int row = c >> 5, off = (c & 31) << 3;
      *(bf16x8*)&a_s[0][row * 264 + off] = *(const bf16x8*)&cu_g[(m0 + row) * 256 + off];
    }
    if (t < 32) {
      int b_ = (int)(m0 >> 14), ii = (int)((m0 >> 7) & 127), j0 = (int)(m0 & 127);
      g_s[0][t] = gatec[(size_t)(b_ * 64 + (ii >> 1)) * 64 + (j0 >> 1) + t];
    }
  }
  __syncthreads();

  const f32x4 zero4 = {0.f, 0.f, 0.f, 0.f};

  for (int it = 0; it < 4; ++it) {
    int cur = it & 1, nxt = cur ^ 1;
    size_t m0i = (size_t)(g * 4 + it) * 64;

    bf16x8 pf[8];
    float gpf = 0.f;
    if (it < 3) {
      size_t m0n = m0i + 64;
      #pragma unroll
      for (int q = 0; q < 8; q++) {
        int c = t + q * 256;
        int row = c >> 5, off = (c & 31) << 3;
        pf[q] = *(const bf16x8*)&cu_g[(m0n + row) * 256 + off];
      }
      if (t < 32) {
        int b_ = (int)(m0n >> 14), ii = (int)((m0n >> 7) & 127), j0 = (int)(m0n & 127);
        gpf = gatec[(size_t)(b_ * 64 + (ii >> 1)) * 64 + (j0 >> 1) + t];
      }
    }

    f32x4 accc[4] = {zero4, zero4, zero4, zero4};
    f32x4 accf[4] = {zero4, zero4, zero4, zero4};
    #pragma unroll
    for (int kt = 0; kt < 8; kt++) {
      #pragma unroll
      for (int mi = 0; mi < 4; mi++) {
        bf16x8 a = *(const bf16x8*)&a_s[cur][(mi * 16 + lr) * 264 + kt * 32 + lg * 8];
        accc[mi] = __builtin_amdgcn_mfma_f32_16x16x32_bf16(a, wb1[kt],  accc[mi], 0, 0, 0);
        accf[mi] = __builtin_amdgcn_mfma_f32_16x16x32_bf16(a, wb12[kt], accf[mi], 0, 0, 0);
      }
    }

    if (it < 3) {
      #pragma unroll
      for (int q = 0; q < 8; q++) {
        int c = t + q * 256;
        int row = c >> 5, off = (c & 31) << 3;
        *(bf16x8*)&a_s[nxt][row * 264 + off] = pf[q];
      }
      if (t < 32) g_s[nxt][t] = gpf;
    }

    #pragma unroll
    for (int mi = 0; mi < 4; mi++) {
      #pragma unroll
      for (int r = 0; r < 4; r++) {
        int row = mi * 16 + lg * 4 + r;
        float gg = g_s[cur][row >> 1];
        float f_out = accf[mi][r] + b12v;
        float c_out = accc[mi][r] + b1v;
        out[(m0i + row) * 256 + n0 + lr] = gg * f_out + (1.f - gg) * c_out;
      }
    }

    if (it < 3) __syncthreads();
  }
}

// ---------------------------------------------------------------------------
extern "C" void kernel_launch(void* const* d_in, const int* in_sizes, int n_in,
                              void* d_out, int out_size, void* d_ws, size_t ws_size,
                              hipStream_t stream) {
  const float* fine        = (const float*)d_in[0];
  const float* coarse      = (const float*)d_in[1];
  const float* gate_w      = (const float*)d_in[2];
  const float* gate_b      = (const float*)d_in[3];
  const float* ss_fine_w   = (const float*)d_in[4];
  const float* ss_fine_b   = (const float*)d_in[5];
  const float* ss_coarse_w = (const float*)d_in[6];
  const float* ss_content_w= (const float*)d_in[7];
  const float* ss_content_b= (const float*)d_in[8];
  const float* W1          = (const float*)d_in[9];
  const float* b1          = (const float*)d_in[10];
  const float* W2          = (const float*)d_in[11];
  const float* b2          = (const float*)d_in[12];
  float* out = (float*)d_out;

  char* ws = (char*)d_ws;
  size_t off = 0;
  float* gatec = (float*)(ws + off); off += 131072;
  float* kff   = (float*)(ws + off); off += (size_t)Nf * 25 * 4;
  float* kfc   = (float*)(ws + off); off += (size_t)Nc * 25 * 4;
  unsigned short* Wt1 = (unsigned short*)(ws + off); off += 65536 * 2;
  unsigned short* Wtf = (unsigned short*)(ws + off); off += 64 * 128 * 2;
  unsigned short* Wtc = (unsigned short*)(ws + off); off += 64 * 256 * 2;
  unsigned short* Wtcnt = (unsigned short*)(ws + off); off += 32 * 576 * 2;
  unsigned short* Wt12 = (unsigned short*)(ws + off); off += 65536 * 2;
  float* b12f = (float*)(ws + off); off += 1024;
  unsigned short* cu_g = (unsigned short*)(ws + off); off += (size_t)Nf * 256 * 2;

  prep_kernel<<<36 + Nc / 4, 256, 0, stream>>>(
      W1, W2, Wt1, Wt12, b12f, b1, b2, ss_fine_w, ss_coarse_w, ss_content_w,
      Wtf, Wtc, Wtcnt, coarse, gate_w, gate_b, gatec);
  embcontent_kernel<<<1024 + 256, 256, 0, stream>>>(
      fine, Wtf, ss_fine_b, coarse, Wtc, Wtcnt, ss_content_b, kff, kfc);
  carafe_kernel<<<dim3(Wf / 8, Hf / 8, Bb), 256, 0, stream>>>(coarse, kff, kfc, cu_g);
  proj_kernel<<<1024, 256, 0, stream>>>(cu_g, gatec, Wt1, b1, Wt12, b12f, out);
}

// Round 12
// 131.402 us; speedup vs baseline: 1.4061x; 1.1326x over previous
//
#include <hip/hip_runtime.h>
#include <math.h>

// Problem constants (fixed by setup_inputs)
constexpr int Bb = 4, Hc = 64, Wc = 64, Cc = 256, Cf = 128, E = 64, KK = 25, F = 256;
constexpr int Hf = 128, Wf = 128;
constexpr int Nc = Bb * Hc * Wc;   // 16384 coarse pixels
constexpr int Nf = Bb * Hf * Wf;   // 65536 fine pixels

typedef __attribute__((ext_vector_type(8))) short bf16x8;
typedef __attribute__((ext_vector_type(4))) float f32x4;

__device__ inline unsigned short f2b(float f) {
  union { float f; unsigned u; } v; v.f = f;
  return (unsigned short)((v.u + 0x7FFF + ((v.u >> 16) & 1)) >> 16);
}

// ---------------------------------------------------------------------------
// prep: 0..15 Wt1 transpose; 16..18 sprep; 19..34 W12 (self-contained);
//       35 b12; 36.. gate
__global__ __launch_bounds__(256) void prep_kernel(
    const float* __restrict__ W1, const float* __restrict__ W2,
    unsigned short* __restrict__ Wt1, unsigned short* __restrict__ Wt12,
    float* __restrict__ b12f, const float* __restrict__ b1,
    const float* __restrict__ b2,
    const float* __restrict__ fw, const float* __restrict__ cw,
    const float* __restrict__ cntw, unsigned short* __restrict__ Wtf,
    unsigned short* __restrict__ Wtc, unsigned short* __restrict__ Wtcnt,
    const float* __restrict__ coarse, const float* __restrict__ gw,
    const float* __restrict__ gb, float* __restrict__ gatec) {
  __shared__ __align__(16) char smem[64 * 72 * 2 * 2];  // 18432 B shared pool
  int idx = blockIdx.x, t = threadIdx.x;

  if (idx < 16) {
    float (*tile)[65] = (float(*)[65])smem;
    int k0 = ((idx >> 2) & 3) * 64, n0 = (idx & 3) * 64;
    int r0 = t >> 6, c = t & 63;
    for (int r = r0; r < 64; r += 4)
      tile[r][c] = W1[(size_t)(k0 + r) * 256 + n0 + c];
    __syncthreads();
    for (int r = r0; r < 64; r += 4)
      Wt1[(size_t)(n0 + r) * 256 + k0 + c] = f2b(tile[c][r]);
  } else if (idx < 19) {
    int sec = idx - 16;
    if (sec == 0) {
      for (int i = t; i < 64 * 128; i += 256) {
        int n = i & 63, k = i >> 6;
        Wtf[n * 128 + k] = f2b(fw[k * 64 + n]);
      }
    } else if (sec == 1) {
      for (int i = t; i < 64 * 256; i += 256) {
        int n = i & 63, k = i >> 6;
        Wtc[n * 256 + k] = f2b(cw[k * 64 + n]);
      }
    } else {
      for (int i = t; i < 32 * 576; i += 256) {
        int n = i & 31, kk = i >> 5;
        Wtcnt[n * 576 + kk] = (n < 25) ? f2b(cntw[kk * 25 + n]) : (unsigned short)0;
      }
    }
  } else if (idx < 35) {
    unsigned short* a_s = (unsigned short*)smem;
    unsigned short* b_s = (unsigned short*)smem + 64 * 72;
    int sub = idx - 19;
    int nbase = (sub & 3) * 64, k0 = (sub >> 2) * 64;
    int wid = t >> 6, lane = t & 63;
    int lr = lane & 15, lg = lane >> 4;
    const f32x4 zero4 = {0.f, 0.f, 0.f, 0.f};
    f32x4 acc[4] = {zero4, zero4, zero4, zero4};

    for (int mc = 0; mc < 4; mc++) {
      for (int i = t; i < 64 * 16; i += 256) {
        int r = i >> 4, c4 = i & 15;
        float4 v = *(const float4*)&W1[(size_t)(k0 + r) * 256 + mc * 64 + c4 * 4];
        *(short4*)&a_s[r * 72 + c4 * 4] =
            make_short4((short)f2b(v.x), (short)f2b(v.y), (short)f2b(v.z), (short)f2b(v.w));
      }
      for (int i = t; i < 64 * 16; i += 256) {
        int m = i >> 4, n4 = i & 15;
        float4 v = *(const float4*)&W2[(size_t)(mc * 64 + m) * 256 + nbase + n4 * 4];
        b_s[(n4 * 4 + 0) * 72 + m] = f2b(v.x);
        b_s[(n4 * 4 + 1) * 72 + m] = f2b(v.y);
        b_s[(n4 * 4 + 2) * 72 + m] = f2b(v.z);
        b_s[(n4 * 4 + 3) * 72 + m] = f2b(v.w);
      }
      __syncthreads();
      #pragma unroll
      for (int kt = 0; kt < 2; kt++) {
        bf16x8 a = *(const bf16x8*)&a_s[(wid * 16 + lr) * 72 + kt * 32 + lg * 8];
        #pragma unroll
        for (int nt = 0; nt < 4; nt++) {
          bf16x8 bb = *(const bf16x8*)&b_s[(nt * 16 + lr) * 72 + kt * 32 + lg * 8];
          acc[nt] = __builtin_amdgcn_mfma_f32_16x16x32_bf16(a, bb, acc[nt], 0, 0, 0);
        }
      }
      __syncthreads();
    }
    #pragma unroll
    for (int nt = 0; nt < 4; nt++)
      #pragma unroll
      for (int r = 0; r < 4; r++)
        Wt12[(size_t)(nbase + nt * 16 + lr) * 256 + k0 + wid * 16 + lg * 4 + r] =
            f2b(acc[nt][r]);
  } else if (idx == 35) {
    int n = t;
    float acc = b2[n];
    #pragma unroll 8
    for (int m = 0; m < 256; m++) acc += b1[m] * W2[(size_t)m * 256 + n];
    b12f[n] = acc;
  } else {
    int px = (idx - 36) * 4 + (t >> 6);
    int lane = t & 63;
    const float4 a = *(const float4*)(coarse + (size_t)px * 256 + lane * 4);
    const float4 w = *(const float4*)(gw + lane * 4);
    float v = a.x * w.x + a.y * w.y + a.z * w.z + a.w * w.w;
    #pragma unroll
    for (int off = 32; off; off >>= 1) v += __shfl_xor(v, off);
    if (lane == 0) gatec[px] = 1.f / (1.f + expf(-(v + gb[0])));
  }
}

// ---------------------------------------------------------------------------
// emb (both resolutions): out_bf16[px][64] = in[px][K] @ Wt[64][K]
template <int K>
__device__ inline void emb_body(const float* __restrict__ in,
                                const unsigned short* __restrict__ Wt,
                                const float* __restrict__ bias,
                                unsigned short* __restrict__ out, int pxb,
                                unsigned short* a_s) {
  constexpr int LDA = K + 8;
  int t = threadIdx.x;
  constexpr int KC = K / 4;
  for (int idx = t; idx < 64 * KC; idx += 256) {
    int px = idx / KC, kc = idx % KC;
    float4 v = *(const float4*)&in[(size_t)(pxb + px) * K + kc * 4];
    *(short4*)&a_s[px * LDA + kc * 4] =
        make_short4((short)f2b(v.x), (short)f2b(v.y), (short)f2b(v.z), (short)f2b(v.w));
  }
  __syncthreads();

  int wid = t >> 6, lane = t & 63;
  int lr = lane & 15, lg = lane >> 4;
  const f32x4 zero4 = {0.f, 0.f, 0.f, 0.f};
  f32x4 acc[4] = {zero4, zero4, zero4, zero4};

  #pragma unroll
  for (int kt = 0; kt < K / 32; kt++) {
    bf16x8 a = *(const bf16x8*)&a_s[(wid * 16 + lr) * LDA + kt * 32 + lg * 8];
    #pragma unroll
    for (int nt = 0; nt < 4; nt++) {
      bf16x8 bb = *(const bf16x8*)&Wt[(size_t)(nt * 16 + lr) * K + kt * 32 + lg * 8];
      acc[nt] = __builtin_amdgcn_mfma_f32_16x16x32_bf16(a, bb, acc[nt], 0, 0, 0);
    }
  }

  #pragma unroll
  for (int nt = 0; nt < 4; nt++) {
    int n = nt * 16 + lr;
    float bv = bias ? bias[n] : 0.f;
    #pragma unroll
    for (int r = 0; r < 4; r++) {
      int px = wid * 16 + lg * 4 + r;
      out[(size_t)(pxb + px) * 64 + n] = f2b(acc[nt][r] + bv);
    }
  }
}

__global__ __launch_bounds__(256) void emb_both_kernel(
    const float* __restrict__ fine, const unsigned short* __restrict__ Wtf,
    const float* __restrict__ fbias, unsigned short* __restrict__ femb,
    const float* __restrict__ coarse, const unsigned short* __restrict__ Wtc,
    unsigned short* __restrict__ cemb) {
  __shared__ __align__(16) unsigned short a_s[64 * 264];
  int idx = blockIdx.x;
  if (idx < Nf / 64) emb_body<128>(fine, Wtf, fbias, femb, idx * 64, a_s);
  else               emb_body<256>(coarse, Wtc, nullptr, cemb, (idx - Nf / 64) * 64, a_s);
}

// ---------------------------------------------------------------------------
// content v2: 16x16 output tile / block; B-frags preloaded in registers
// (18 per nt-phase), reused across 4 M-tiles -> 8 MFMA per B-load.
__global__ __launch_bounds__(256) void content_both_kernel(
    const unsigned short* __restrict__ femb, const unsigned short* __restrict__ cemb,
    const unsigned short* __restrict__ Wtcnt, const float* __restrict__ cb,
    float* __restrict__ kff, float* __restrict__ kfc) {
  __shared__ __align__(16) unsigned short a_s[324 * 72];  // 46656 B (18x18 halo)
  int idx = blockIdx.x, t = threadIdx.x;
  const unsigned short* emb;
  float* out;
  int b, i0, j0, Hd, Wd;
  if (idx < 256) {
    b = idx >> 6; int rem = idx & 63;
    i0 = (rem >> 3) * 16; j0 = (rem & 7) * 16; Hd = 128; Wd = 128;
    emb = femb; out = kff;
  } else {
    int i2 = idx - 256;
    b = i2 >> 4; int rem = i2 & 15;
    i0 = (rem >> 2) * 16; j0 = (rem & 3) * 16; Hd = 64; Wd = 64;
    emb = cemb; out = kfc;
  }

  // stage 18x18 halo x 64 ch (bf16, 8B chunks)
  for (int i = t; i < 324 * 16; i += 256) {
    int cell = i >> 4, ck = i & 15;
    int gi = i0 - 1 + cell / 18;
    int gj = j0 - 1 + cell % 18;
    short4 v = make_short4(0, 0, 0, 0);
    if (gi >= 0 && gi < Hd && gj >= 0 && gj < Wd)
      v = *(const short4*)&emb[(size_t)((b * Hd + gi) * Wd + gj) * 64 + ck * 4];
    *(short4*)&a_s[cell * 72 + ck * 4] = v;
  }
  __syncthreads();

  int wid = t >> 6, lane = t & 63;
  int lr = lane & 15, lg = lane >> 4;
  const f32x4 zero4 = {0.f, 0.f, 0.f, 0.f};
  f32x4 acc[4][2];
  #pragma unroll
  for (int mt = 0; mt < 4; mt++)
    #pragma unroll
    for (int nt = 0; nt < 2; nt++) acc[mt][nt] = zero4;

  // nt-phased: preload 18 B-frags (tap x kt) into regs, sweep 4 M-tiles
  #pragma unroll
  for (int nt = 0; nt < 2; nt++) {
    bf16x8 wb[9][2];
    #pragma unroll
    for (int tap = 0; tap < 9; tap++)
      #pragma unroll
      for (int kt = 0; kt < 2; kt++)
        wb[tap][kt] = *(const bf16x8*)&Wtcnt[(size_t)(nt * 16 + lr) * 576 + tap * 64 + kt * 32 + lg * 8];

    #pragma unroll
    for (int mt = 0; mt < 4; mt++) {
      int m = wid * 4 + mt;             // output row (pi) of the 16x16 tile
      #pragma unroll
      for (int di = 0; di < 3; di++) {
        #pragma unroll
        for (int dj = 0; dj < 3; dj++) {
          int cell = (m + di) * 18 + (lr + dj);
          int tap = di * 3 + dj;
          #pragma unroll
          for (int kt = 0; kt < 2; kt++) {
            bf16x8 a = *(const bf16x8*)&a_s[cell * 72 + kt * 32 + lg * 8];
            acc[mt][nt] = __builtin_amdgcn_mfma_f32_16x16x32_bf16(a, wb[tap][kt], acc[mt][nt], 0, 0, 0);
          }
        }
      }
    }
  }

  // store: output px = (pi = m, pj = lg*4+r), ch = nt*16+lr
  #pragma unroll
  for (int mt = 0; mt < 4; mt++) {
    int m = wid * 4 + mt;
    int gi = i0 + m;
    #pragma unroll
    for (int nt = 0; nt < 2; nt++) {
      int ch = nt * 16 + lr;
      if (ch < 25) {
        float bv = cb[ch];
        #pragma unroll
        for (int r = 0; r < 4; r++) {
          int gj = j0 + lg * 4 + r;
          out[(size_t)((b * Hd + gi) * Wd + gj) * 25 + ch] = acc[mt][nt][r] + bv;
        }
      }
    }
  }
}

// ---------------------------------------------------------------------------
// carafe (64 px / block): 8x8 fine tile -> 8x8 coarse window. cu_g bf16.
__global__ __launch_bounds__(256) void carafe_kernel(
    const float* __restrict__ coarse, const float* __restrict__ kff,
    const float* __restrict__ kfc, unsigned short* __restrict__ cu_g) {
  __shared__ __align__(16) unsigned short buf[256 * 72];   // win_t, then cu_s
  __shared__ __align__(16) unsigned short m_ext[64 * 72];  // 9216 B
  unsigned short* win_t = buf;
  unsigned short* cu_s  = buf;

  int t = threadIdx.x;
  int b = blockIdx.z;
  int i0 = blockIdx.y * 8, j0 = blockIdx.x * 8;
  int hw0 = (i0 >> 1) - 2, ww0 = (j0 >> 1) - 2;

  {
    #pragma unroll
    for (int p0 = 0; p0 < 64; p0 += 4) {
      unsigned short vals[4];
      #pragma unroll
      for (int q = 0; q < 4; q++) {
        int p = p0 + q;
        int h = hw0 + (p >> 3), w = ww0 + (p & 7);
        float v = 0.f;
        if (h >= 0 && h < 64 && w >= 0 && w < 64)
          v = coarse[(size_t)((b * 64 + h) * 64 + w) * 256 + t];
        vals[q] = f2b(v);
      }
      *(short4*)&win_t[t * 72 + p0] =
          make_short4((short)vals[0], (short)vals[1], (short)vals[2], (short)vals[3]);
    }
  }
  if (t < 64) {
    int ti = t >> 3, tj = t & 7;
    int i = i0 + ti, j = j0 + tj;
    size_t fpx = (size_t)((b * 128 + i) * 128 + j);
    size_t cpx = (size_t)((b * 64 + (i >> 1)) * 64 + (j >> 1));
    float v[25];
    float mx = -1e30f;
    #pragma unroll
    for (int m = 0; m < 25; m++) {
      v[m] = kff[fpx * 25 + m] + kfc[cpx * 25 + m];
      mx = fmaxf(mx, v[m]);
    }
    float s = 0.f;
    #pragma unroll
    for (int m = 0; m < 25; m++) { v[m] = expf(v[m] - mx); s += v[m]; }
    float inv = 1.f / s;
    unsigned* row32 = (unsigned*)&m_ext[t * 72];
    #pragma unroll
    for (int q = 0; q < 36; q++) row32[q] = 0;
    int wib = ti >> 1, wjb = tj >> 1;
    #pragma unroll
    for (int di = 0; di < 5; di++)
      #pragma unroll
      for (int dj = 0; dj < 5; dj++)
        m_ext[t * 72 + (wib + di) * 8 + (wjb + dj)] = f2b(v[di * 5 + dj] * inv);
  }
  __syncthreads();

  int wid = t >> 6, lane = t & 63;
  int lr = lane & 15, lg = lane >> 4;
  const f32x4 zero4 = {0.f, 0.f, 0.f, 0.f};

  f32x4 acc0[4][4];
  #pragma unroll
  for (int mi = 0; mi < 4; mi++)
    #pragma unroll
    for (int ni = 0; ni < 4; ni++) acc0[mi][ni] = zero4;
  #pragma unroll
  for (int kt = 0; kt < 2; kt++) {
    bf16x8 am[4];
    #pragma unroll
    for (int mi = 0; mi < 4; mi++)
      am[mi] = *(const bf16x8*)&m_ext[(mi * 16 + lr) * 72 + kt * 32 + lg * 8];
    #pragma unroll
    for (int ni = 0; ni < 4; ni++) {
      bf16x8 bb = *(const bf16x8*)&win_t[(size_t)(wid * 64 + ni * 16 + lr) * 72 + kt * 32 + lg * 8];
      #pragma unroll
      for (int mi = 0; mi < 4; mi++)
        acc0[mi][ni] = __builtin_amdgcn_mfma_f32_16x16x32_bf16(am[mi], bb, acc0[mi][ni], 0, 0, 0);
    }
  }
  __syncthreads();

  #pragma unroll
  for (int mi = 0; mi < 4; mi++)
    #pragma unroll
    for (int ni = 0; ni < 4; ni++)
      #pragma unroll
      for (int r = 0; r < 4; r++)
        cu_s[(mi * 16 + lg * 4 + r) * 264 + wid * 64 + ni * 16 + lr] = f2b(acc0[mi][ni][r]);
  __syncthreads();

  for (int c = t; c < 2048; c += 256) {
    int p = c >> 5, off = (c & 31) << 3;
    int gi = i0 + (p >> 3), gj = j0 + (p & 7);
    bf16x8 v = *(const bf16x8*)&cu_s[p * 264 + off];
    *(bf16x8*)&cu_g[(size_t)((b * 128 + gi) * 128 + gj) * 256 + off] = v;
  }
}

// ---------------------------------------------------------------------------
// proj: persistent 4-tile pipeline, weights in regs, LDS double buffer.
__global__ __launch_bounds__(256, 2) void proj_kernel(
    const unsigned short* __restrict__ cu_g, const float* __restrict__ gatec,
    const unsigned short* __restrict__ Wt1, const float* __restrict__ b1,
    const unsigned short* __restrict__ Wt12, const float* __restrict__ b12,
    float* __restrict__ out) {
  __shared__ __align__(16) unsigned short a_s[2][64 * 264];
  __shared__ float g_s[2][32];
  int t = threadIdx.x;
  int bid = blockIdx.x;
  int cg = bid >> 8;
  int g  = bid & 255;
  int wid = t >> 6, lane = t & 63;
  int lr = lane & 15, lg = lane >> 4;
  int n0 = cg * 64 + wid * 16;

  bf16x8 wb1[8], wb12[8];
  #pragma unroll
  for (int kt = 0; kt < 8; kt++) {
    size_t wrow = (size_t)(n0 + lr) * 256 + kt * 32 + lg * 8;
    wb1[kt]  = *(const bf16x8*)&Wt1[wrow];
    wb12[kt] = *(const bf16x8*)&Wt12[wrow];
  }
  float b1v  = b1[n0 + lr];
  float b12v = b12[n0 + lr];

  {
    size_t m0 = (size_t)g * 256;
    for (int c = t; c < 2048; c += 256) {
      int row = c >> 5, off = (c & 31) << 3;
      *(bf16x8*)&a_s[0][row * 264 + off] = *(const bf16x8*)&cu_g[(m0 + row) * 256 + off];
    }
    if (t < 32) {
      int b_ = (int)(m0 >> 14), ii = (int)((m0 >> 7) & 127), j0 = (int)(m0 & 127);
      g_s[0][t] = gatec[(size_t)(b_ * 64 + (ii >> 1)) * 64 + (j0 >> 1) + t];
    }
  }
  __syncthreads();

  const f32x4 zero4 = {0.f, 0.f, 0.f, 0.f};

  for (int it = 0; it < 4; ++it) {
    int cur = it & 1, nxt = cur ^ 1;
    size_t m0i = (size_t)(g * 4 + it) * 64;

    bf16x8 pf[8];
    float gpf = 0.f;
    if (it < 3) {
      size_t m0n = m0i + 64;
      #pragma unroll
      for (int q = 0; q < 8; q++) {
        int c = t + q * 256;
        int row = c >> 5, off = (c & 31) << 3;
        pf[q] = *(const bf16x8*)&cu_g[(m0n + row) * 256 + off];
      }
      if (t < 32) {
        int b_ = (int)(m0n >> 14), ii = (int)((m0n >> 7) & 127), j0 = (int)(m0n & 127);
        gpf = gatec[(size_t)(b_ * 64 + (ii >> 1)) * 64 + (j0 >> 1) + t];
      }
    }

    f32x4 accc[4] = {zero4, zero4, zero4, zero4};
    f32x4 accf[4] = {zero4, zero4, zero4, zero4};
    #pragma unroll
    for (int kt = 0; kt < 8; kt++) {
      #pragma unroll
      for (int mi = 0; mi < 4; mi++) {
        bf16x8 a = *(const bf16x8*)&a_s[cur][(mi * 16 + lr) * 264 + kt * 32 + lg * 8];
        accc[mi] = __builtin_amdgcn_mfma_f32_16x16x32_bf16(a, wb1[kt],  accc[mi], 0, 0, 0);
        accf[mi] = __builtin_amdgcn_mfma_f32_16x16x32_bf16(a, wb12[kt], accf[mi], 0, 0, 0);
      }
    }

    if (it < 3) {
      #pragma unroll
      for (int q = 0; q < 8; q++) {
        int c = t + q * 256;
        int row = c >> 5, off = (c & 31) << 3;
        *(bf16x8*)&a_s[nxt][row * 264 + off] = pf[q];
      }
      if (t < 32) g_s[nxt][t] = gpf;
    }

    #pragma unroll
    for (int mi = 0; mi < 4; mi++) {
      #pragma unroll
      for (int r = 0; r < 4; r++) {
        int row = mi * 16 + lg * 4 + r;
        float gg = g_s[cur][row >> 1];
        float f_out = accf[mi][r] + b12v;
        float c_out = accc[mi][r] + b1v;
        out[(m0i + row) * 256 + n0 + lr] = gg * f_out + (1.f - gg) * c_out;
      }
    }

    if (it < 3) __syncthreads();
  }
}

// ---------------------------------------------------------------------------
extern "C" void kernel_launch(void* const* d_in, const int* in_sizes, int n_in,
                              void* d_out, int out_size, void* d_ws, size_t ws_size,
                              hipStream_t stream) {
  const float* fine        = (const float*)d_in[0];
  const float* coarse      = (const float*)d_in[1];
  const float* gate_w      = (const float*)d_in[2];
  const float* gate_b      = (const float*)d_in[3];
  const float* ss_fine_w   = (const float*)d_in[4];
  const float* ss_fine_b   = (const float*)d_in[5];
  const float* ss_coarse_w = (const float*)d_in[6];
  const float* ss_content_w= (const float*)d_in[7];
  const float* ss_content_b= (const float*)d_in[8];
  const float* W1          = (const float*)d_in[9];
  const float* b1          = (const float*)d_in[10];
  const float* W2          = (const float*)d_in[11];
  const float* b2          = (const float*)d_in[12];
  float* out = (float*)d_out;

  char* ws = (char*)d_ws;
  size_t off = 0;
  float* gatec = (float*)(ws + off); off += 131072;
  unsigned short* femb = (unsigned short*)(ws + off); off += (size_t)Nf * 64 * 2;
  unsigned short* cemb = (unsigned short*)(ws + off); off += (size_t)Nc * 64 * 2;
  float* kff   = (float*)(ws + off); off += (size_t)Nf * 25 * 4;
  float* kfc   = (float*)(ws + off); off += (size_t)Nc * 25 * 4;
  unsigned short* Wt1 = (unsigned short*)(ws + off); off += 65536 * 2;
  unsigned short* Wtf = (unsigned short*)(ws + off); off += 64 * 128 * 2;
  unsigned short* Wtc = (unsigned short*)(ws + off); off += 64 * 256 * 2;
  unsigned short* Wtcnt = (unsigned short*)(ws + off); off += 32 * 576 * 2;
  unsigned short* Wt12 = (unsigned short*)(ws + off); off += 65536 * 2;
  float* b12f = (float*)(ws + off); off += 1024;
  unsigned short* cu_g = (unsigned short*)(ws + off); off += (size_t)Nf * 256 * 2;

  prep_kernel<<<36 + Nc / 4, 256, 0, stream>>>(
      W1, W2, Wt1, Wt12, b12f, b1, b2, ss_fine_w, ss_coarse_w, ss_content_w,
      Wtf, Wtc, Wtcnt, coarse, gate_w, gate_b, gatec);
  emb_both_kernel<<<Nf / 64 + Nc / 64, 256, 0, stream>>>(
      fine, Wtf, ss_fine_b, femb, coarse, Wtc, cemb);
  content_both_kernel<<<256 + 64, 256, 0, stream>>>(
      femb, cemb, Wtcnt, ss_content_b, kff, kfc);
  carafe_kernel<<<dim3(Wf / 8, Hf / 8, Bb), 256, 0, stream>>>(coarse, kff, kfc, cu_g);
  proj_kernel<<<1024, 256, 0, stream>>>(cu_g, gatec, Wt1, b1, Wt12, b12f, out);
}